// Round 2
// baseline (57501.074 us; speedup 1.0000x reference)
//
#include <hip/hip_runtime.h>

// Problem constants
#define B_  128
#define T_  512
#define I_  512
#define H_  1024
#define G4  4096   // 4*H

typedef __attribute__((ext_vector_type(8))) short   short8;
typedef __attribute__((ext_vector_type(4))) short   short4v;
typedef __attribute__((ext_vector_type(4))) float   f32x4;

__device__ __forceinline__ float bf2f(short u){
  return __uint_as_float(((unsigned)(unsigned short)u) << 16);
}
__device__ __forceinline__ short f2bf(float f){
  unsigned u = __float_as_uint(f);
  unsigned r = (u + 0x7FFFu + ((u >> 16) & 1u)) >> 16;  // RNE
  return (short)r;
}
__device__ __forceinline__ float sigm(float x){ return 1.0f/(1.0f + __expf(-x)); }
__device__ __forceinline__ float tanh_(float x){ return 1.0f - 2.0f/(__expf(2.0f*x) + 1.0f); }

// ---------------- fp32 -> bf16 elementwise convert (vectorized x4) ----------------
__global__ __launch_bounds__(256) void cvt_bf16(const float* __restrict__ in,
                                                short* __restrict__ out, int nq){
  int i = blockIdx.x*256 + threadIdx.x;
  if (i >= nq) return;
  float4 v = ((const float4*)in)[i];
  short4v o; o.x = f2bf(v.x); o.y = f2bf(v.y); o.z = f2bf(v.z); o.w = f2bf(v.w);
  ((short4v*)out)[i] = o;
}

// ---------------- W_hh fp32 [4096][1024] -> bf16 MFMA-fragment-swizzled ----------------
// out chunk index c = ((g*64 + jf)*32 + s)*64 + l ; chunk = 8 bf16 (16B)
// represents W[g*1024 + jf*16 + (l&15)][s*32 + (l>>4)*8 + e]
__global__ __launch_bounds__(256) void swz_whh(const float* __restrict__ W,
                                               short* __restrict__ out){
  int c = blockIdx.x*256 + threadIdx.x;      // 0 .. 524287
  int l = c & 63, s = (c >> 6) & 31, jf = (c >> 11) & 63, g = c >> 17;
  long row = (long)(g*1024 + jf*16 + (l & 15));
  int col = s*32 + (l >> 4)*8;
  const float* src = W + row*H_ + col;
  short8 o;
#pragma unroll
  for (int e = 0; e < 8; ++e) o[e] = f2bf(src[e]);
  ((short8*)out)[c] = o;
}

// ---------------- projection GEMM: C[m,n] = sum_k A[m,k]*W[n,k] + bih[n]+bhh[n] ----------------
// A: [M,K] bf16 row-major (M = B*T, rows m = b*T+t), W: [4096,K] bf16 row-major.
// Output written in scan-swizzled xg layout:
//   idx = ((((t*8 + bt)*64 + jf)*4 + g)*256 + bl*16 + jl
// Tiles 128x128, BK=32, 256 thr (4 waves 2x2, 64x64/wave), reg-staged dbuf LDS.
template<int K>
__global__ __launch_bounds__(256) void proj_gemm(const short* __restrict__ A,
                                                 const short* __restrict__ W,
                                                 const float* __restrict__ bih,
                                                 const float* __restrict__ bhh,
                                                 short* __restrict__ C){
  __shared__ short lds[2][2][128*40];  // [buf][A/B][row*40+col], pad 40 kills conflicts
  const int tid = threadIdx.x;
  const int l  = tid & 63, wv = tid >> 6;
  const int wm = wv >> 1,  wn = wv & 1;
  const int nt = blockIdx.x, mt = blockIdx.y;
  const int r0 = tid >> 2, cb = (tid & 3) * 8;
  const short* Ab = A + (long)(mt*128 + r0)*K + cb;
  const short* Wb = W + (long)(nt*128 + r0)*K + cb;
  const int lo  = r0*40 + cb;
  const int lo2 = lo + 64*40;
  const int NK = K/32;

  short8 pa0 = *(const short8*)(Ab);
  short8 pa1 = *(const short8*)(Ab + 64*K);
  short8 pb0 = *(const short8*)(Wb);
  short8 pb1 = *(const short8*)(Wb + 64*K);
  *(short8*)&lds[0][0][lo]  = pa0;
  *(short8*)&lds[0][0][lo2] = pa1;
  *(short8*)&lds[0][1][lo]  = pb0;
  *(short8*)&lds[0][1][lo2] = pb1;

  f32x4 acc[4][4];
  f32x4 z = {0.f,0.f,0.f,0.f};
#pragma unroll
  for (int i = 0; i < 4; ++i)
#pragma unroll
    for (int j = 0; j < 4; ++j) acc[i][j] = z;

  for (int kt = 0; kt < NK; ++kt){
    __syncthreads();
    if (kt + 1 < NK){
      pa0 = *(const short8*)(Ab + (kt+1)*32);
      pa1 = *(const short8*)(Ab + (kt+1)*32 + 64*K);
      pb0 = *(const short8*)(Wb + (kt+1)*32);
      pb1 = *(const short8*)(Wb + (kt+1)*32 + 64*K);
    }
    const short* As = lds[kt & 1][0];
    const short* Bs = lds[kt & 1][1];
    short8 bfr[4];
#pragma unroll
    for (int nf = 0; nf < 4; ++nf)
      bfr[nf] = *(const short8*)&Bs[(wn*64 + nf*16 + (l & 15))*40 + (l >> 4)*8];
#pragma unroll
    for (int mf = 0; mf < 4; ++mf){
      short8 af = *(const short8*)&As[(wm*64 + mf*16 + (l & 15))*40 + (l >> 4)*8];
#pragma unroll
      for (int nf = 0; nf < 4; ++nf)
        acc[mf][nf] = __builtin_amdgcn_mfma_f32_16x16x32_bf16(af, bfr[nf], acc[mf][nf], 0, 0, 0);
    }
    if (kt + 1 < NK){
      int nb = (kt + 1) & 1;
      *(short8*)&lds[nb][0][lo]  = pa0;
      *(short8*)&lds[nb][0][lo2] = pa1;
      *(short8*)&lds[nb][1][lo]  = pb0;
      *(short8*)&lds[nb][1][lo2] = pb1;
    }
  }

  const int mrow0 = mt*128 + wm*64;
  const int ncol0 = nt*128 + wn*64;
#pragma unroll
  for (int nf = 0; nf < 4; ++nf){
    int n = ncol0 + nf*16 + (l & 15);      // n = g*1024 + jf*16 + jl
    int g  = n >> 10;
    int jfn = (n >> 4) & 63;
    int jl  = n & 15;
    float bs = bih[n] + bhh[n];
#pragma unroll
    for (int mf = 0; mf < 4; ++mf){
#pragma unroll
      for (int r = 0; r < 4; ++r){
        int m = mrow0 + mf*16 + (l >> 4)*4 + r;   // C/D: row=(l>>4)*4+r, col=l&15
        int b = m >> 9, t = m & 511;
        long idx = ((((long)t*8 + (b >> 4))*64 + jfn)*4 + g)*256 + (b & 15)*16 + jl;
        C[idx] = f2bf(acc[mf][nf][r] + bs);
      }
    }
  }
}

// ---------------- persistent LSTM scan (one launch per layer) ----------------
// grid (jf=64, bt=8) = 512 blocks x 256 thr; 2 blocks/CU co-resident.
// W_hh slice (64 rows x 1024 K = 128KB/block) register-resident (128 VGPR/thread).
// c state register-resident. Per step: read h frags (32KB/block from L3), 32 MFMA/wave
// (4-way K-split), LDS reduce, elementwise, write h slice, flag-barrier within bt-group.
// h carried in MFMA A-fragment layout: chunk ((b>>4)*32 + s)*64 + (kq*16 + (b&15)),
// elem e  <->  h[b][s*32 + kq*8 + e]  (bf16).
template<int LAYER>
__global__ __launch_bounds__(256, 2) void lstm_scan(
    short* __restrict__ hb0, short* __restrict__ hb1,
    const short* __restrict__ Wsw, const short* __restrict__ xg,
    const float* __restrict__ om, const float* __restrict__ hm, const float* __restrict__ cm,
    short* __restrict__ out0, float* __restrict__ dout,
    int* __restrict__ flags)     // [8 bt][512 t][64 jf] ints, pre-zeroed
{
  const int tid = threadIdx.x;
  const int l = tid & 63, wv = tid >> 6;
  const int jf = blockIdx.x, bt = blockIdx.y;

  // ---- load W fragments once (register-resident for all 512 steps) ----
  short8 w[4][8];
#pragma unroll
  for (int g = 0; g < 4; ++g){
    const short8* wp = (const short8*)Wsw + ((g*64 + jf)*32 + wv*8)*64 + l;
#pragma unroll
    for (int ks = 0; ks < 8; ++ks) w[g][ks] = wp[ks*64];
  }

  // ---- elementwise-role constants ----
  const int bl = tid >> 4, jl = tid & 15;
  const int jcol = jf*16 + jl;
  const long bj = (long)(bt*16 + bl)*H_ + jcol;
  const float mo = om[bj], mh = hm[bj], mc = cm[bj];
  float c = 0.f;
  const int lsrc = ((bl >> 2) << 4) | jl;   // lane holding acc row bl, col jl
  const int rr = bl & 3;
  const int hchunk = (bt*32 + wv*8)*64 + l;
  const long hn_idx = ((long)(bt*32 + (jcol >> 5))*64 + ((jcol >> 3) & 3)*16 + bl)*8 + (jcol & 7);

  __shared__ float red[16][256];
  int* fl = flags + (long)bt*T_*64;

  for (int t = 0; t < T_; ++t){
    // ---- gates GEMM: each wave K-slice 256, all 4 gates ----
    const short8* hp = (const short8*)(t & 1 ? hb1 : hb0) + hchunk;
    short8 a[8];
#pragma unroll
    for (int ks = 0; ks < 8; ++ks) a[ks] = hp[ks*64];

    f32x4 acc[4];
    f32x4 z = {0.f,0.f,0.f,0.f};
#pragma unroll
    for (int g = 0; g < 4; ++g) acc[g] = z;
#pragma unroll
    for (int g = 0; g < 4; ++g)
#pragma unroll
      for (int ks = 0; ks < 8; ++ks)
        acc[g] = __builtin_amdgcn_mfma_f32_16x16x32_bf16(a[ks], w[g][ks], acc[g], 0, 0, 0);

#pragma unroll
    for (int g = 0; g < 4; ++g)
#pragma unroll
      for (int r = 0; r < 4; ++r)
        red[g*4 + r][tid] = acc[g][r];
    __syncthreads();

    // ---- elementwise (thread owns (bl, jl)) ----
    const short* xgp = xg + (((long)t*8 + bt)*64 + jf)*1024;
    float gate[4];
#pragma unroll
    for (int g = 0; g < 4; ++g){
      float s = red[g*4+rr][lsrc] + red[g*4+rr][64+lsrc]
              + red[g*4+rr][128+lsrc] + red[g*4+rr][192+lsrc];
      gate[g] = s + bf2f(xgp[g*256 + tid]);
    }
    float ii = sigm(gate[0]);
    float ff = sigm(gate[1]);
    float gg = tanh_(gate[2]);
    float oo = sigm(gate[3]);
    float c2 = ff*c + ii*gg;
    float h2 = oo*tanh_(c2);
    c = c2*mc;
    float hn = h2*mh;

    short* hnx = (t & 1) ? hb0 : hb1;
    hnx[hn_idx] = f2bf(hn);

    if (LAYER == 0){
      out0[((long)(bt*16 + bl)*T_ + t)*H_ + jcol] = f2bf(h2*mo);
    } else {
      dout[((long)(bt*16 + bl)*T_ + t)*H_ + jcol] = h2*mo;
      if (t == T_ - 1){
        dout[(long)B_*T_*H_ + bj] = hn;                    // hf
        dout[(long)B_*T_*H_ + (long)B_*H_ + bj] = c;       // cf
      }
    }

    if (t == T_ - 1) break;

    // ---- bt-group barrier: release h, arrive, wait for all 64 jf blocks ----
    __builtin_amdgcn_fence(__ATOMIC_RELEASE, "agent");   // flush h stores device-wide
    __syncthreads();                                      // all threads released
    if (tid == 0)
      __hip_atomic_store(&fl[t*64 + jf], 1, __ATOMIC_RELAXED, __HIP_MEMORY_SCOPE_AGENT);
    if (tid < 64){
      int guard = 0;
      while (__hip_atomic_load(&fl[t*64 + tid], __ATOMIC_RELAXED, __HIP_MEMORY_SCOPE_AGENT) == 0){
        if (++guard > (1 << 20)) break;   // safety: wrong-answer instead of hang
      }
    }
    __syncthreads();
    __builtin_amdgcn_fence(__ATOMIC_ACQUIRE, "agent");   // invalidate stale L1/L2 before h reads
  }
}

extern "C" void kernel_launch(void* const* d_in, const int* in_sizes, int n_in,
                              void* d_out, int out_size, void* d_ws, size_t ws_size,
                              hipStream_t stream){
  const float* x    = (const float*)d_in[0];
  const float* Wih0 = (const float*)d_in[1];
  const float* Whh0 = (const float*)d_in[2];
  const float* bih0 = (const float*)d_in[3];
  const float* bhh0 = (const float*)d_in[4];
  const float* Wih1 = (const float*)d_in[5];
  const float* Whh1 = (const float*)d_in[6];
  const float* bih1 = (const float*)d_in[7];
  const float* bhh1 = (const float*)d_in[8];
  const float* omsk = (const float*)d_in[9];
  const float* hmsk = (const float*)d_in[10];
  const float* cmsk = (const float*)d_in[11];
  float* out = (float*)d_out;

  char* p = (char*)d_ws;
  auto alloc = [&](size_t bytes)->char*{
    char* r = p; p += (bytes + 255) & ~(size_t)255; return r;
  };
  short* xg      = (short*)alloc((size_t)65536*4096*2);   // swizzled xg (shared by both layers)
  short* x_bf    = (short*)alloc((size_t)33554432*2);     // x as bf16, [b*T+t][512]
  short* out0_bf = (short*)alloc((size_t)67108864*2);     // layer-0 outputs, [b*T+t][1024] bf16
  short* wih0_bf = (short*)alloc((size_t)2097152*2);
  short* wih1_bf = (short*)alloc((size_t)4194304*2);
  short* whh0_sw = (short*)alloc((size_t)4194304*2);
  short* whh1_sw = (short*)alloc((size_t)4194304*2);
  short* hb0     = (short*)alloc((size_t)131072*2);
  short* hb1     = (short*)alloc((size_t)131072*2);
  int*   flags0  = (int*)alloc((size_t)8*512*64*4);       // 1 MB
  int*   flags1  = (int*)alloc((size_t)8*512*64*4);       // 1 MB
  if ((size_t)(p - (char*)d_ws) > ws_size) return;   // workspace too small — bail

  // barrier flags must be zero at scan start (deterministic across graph replays)
  hipMemsetAsync(flags0, 0, (size_t)8*512*64*4, stream);
  hipMemsetAsync(flags1, 0, (size_t)8*512*64*4, stream);

  // converts / weight swizzles
  cvt_bf16<<<33554432/4/256, 256, 0, stream>>>(x,    x_bf,    33554432/4);
  cvt_bf16<<<2097152/4/256,  256, 0, stream>>>(Wih0, wih0_bf, 2097152/4);
  cvt_bf16<<<4194304/4/256,  256, 0, stream>>>(Wih1, wih1_bf, 4194304/4);
  swz_whh <<<524288/256,     256, 0, stream>>>(Whh0, whh0_sw);
  swz_whh <<<524288/256,     256, 0, stream>>>(Whh1, whh1_sw);

  // ---- layer 0 ----
  proj_gemm<512><<<dim3(32, 512), 256, 0, stream>>>(x_bf, wih0_bf, bih0, bhh0, xg);
  hipMemsetAsync(hb0, 0, 262144, stream);
  lstm_scan<0><<<dim3(64, 8), 256, 0, stream>>>(hb0, hb1, whh0_sw, xg,
      omsk, hmsk, cmsk, out0_bf, nullptr, flags0);

  // ---- layer 1 ----
  proj_gemm<1024><<<dim3(32, 512), 256, 0, stream>>>(out0_bf, wih1_bf, bih1, bhh1, xg);
  hipMemsetAsync(hb0, 0, 262144, stream);
  lstm_scan<1><<<dim3(64, 8), 256, 0, stream>>>(hb0, hb1, whh1_sw, xg,
      omsk + 131072, hmsk + 131072, cmsk + 131072, nullptr, out, flags1);
}

// Round 3
// 9625.828 us; speedup vs baseline: 5.9736x; 5.9736x over previous
//
#include <hip/hip_runtime.h>

// Problem constants
#define B_  128
#define T_  512
#define I_  512
#define H_  1024
#define G4  4096   // 4*H

typedef __attribute__((ext_vector_type(8))) short   short8;
typedef __attribute__((ext_vector_type(4))) short   short4v;
typedef __attribute__((ext_vector_type(4))) float   f32x4;
typedef unsigned long long u64;

__device__ __forceinline__ float bf2f(short u){
  return __uint_as_float(((unsigned)(unsigned short)u) << 16);
}
__device__ __forceinline__ short f2bf(float f){
  unsigned u = __float_as_uint(f);
  unsigned r = (u + 0x7FFFu + ((u >> 16) & 1u)) >> 16;  // RNE
  return (short)r;
}
__device__ __forceinline__ float sigm(float x){ return 1.0f/(1.0f + __expf(-x)); }
__device__ __forceinline__ float tanh_(float x){ return 1.0f - 2.0f/(__expf(2.0f*x) + 1.0f); }

// ---------------- fp32 -> bf16 elementwise convert (vectorized x4) ----------------
__global__ __launch_bounds__(256) void cvt_bf16(const float* __restrict__ in,
                                                short* __restrict__ out, int nq){
  int i = blockIdx.x*256 + threadIdx.x;
  if (i >= nq) return;
  float4 v = ((const float4*)in)[i];
  short4v o; o.x = f2bf(v.x); o.y = f2bf(v.y); o.z = f2bf(v.z); o.w = f2bf(v.w);
  ((short4v*)out)[i] = o;
}

// ---------------- W_hh fp32 [4096][1024] -> bf16 MFMA-fragment-swizzled ----------------
// out chunk index c = ((g*64 + jf)*32 + s)*64 + l ; chunk = 8 bf16 (16B)
// represents W[g*1024 + jf*16 + (l&15)][s*32 + (l>>4)*8 + e]
__global__ __launch_bounds__(256) void swz_whh(const float* __restrict__ W,
                                               short* __restrict__ out){
  int c = blockIdx.x*256 + threadIdx.x;      // 0 .. 524287
  int l = c & 63, s = (c >> 6) & 31, jf = (c >> 11) & 63, g = c >> 17;
  long row = (long)(g*1024 + jf*16 + (l & 15));
  int col = s*32 + (l >> 4)*8;
  const float* src = W + row*H_ + col;
  short8 o;
#pragma unroll
  for (int e = 0; e < 8; ++e) o[e] = f2bf(src[e]);
  ((short8*)out)[c] = o;
}

// ---------------- projection GEMM: C[m,n] = sum_k A[m,k]*W[n,k] + bih[n]+bhh[n] ----------------
// A: [M,K] bf16 row-major (M = B*T, rows m = b*T+t), W: [4096,K] bf16 row-major.
// Output written in scan-swizzled xg layout:
//   idx = ((((t*8 + bt)*64 + jf)*4 + g)*256 + bl*16 + jl
// Tiles 128x128, BK=32, 256 thr (4 waves 2x2, 64x64/wave), reg-staged dbuf LDS.
template<int K>
__global__ __launch_bounds__(256) void proj_gemm(const short* __restrict__ A,
                                                 const short* __restrict__ W,
                                                 const float* __restrict__ bih,
                                                 const float* __restrict__ bhh,
                                                 short* __restrict__ C){
  __shared__ short lds[2][2][128*40];  // [buf][A/B][row*40+col], pad 40 kills conflicts
  const int tid = threadIdx.x;
  const int l  = tid & 63, wv = tid >> 6;
  const int wm = wv >> 1,  wn = wv & 1;
  const int nt = blockIdx.x, mt = blockIdx.y;
  const int r0 = tid >> 2, cb = (tid & 3) * 8;
  const short* Ab = A + (long)(mt*128 + r0)*K + cb;
  const short* Wb = W + (long)(nt*128 + r0)*K + cb;
  const int lo  = r0*40 + cb;
  const int lo2 = lo + 64*40;
  const int NK = K/32;

  short8 pa0 = *(const short8*)(Ab);
  short8 pa1 = *(const short8*)(Ab + 64*K);
  short8 pb0 = *(const short8*)(Wb);
  short8 pb1 = *(const short8*)(Wb + 64*K);
  *(short8*)&lds[0][0][lo]  = pa0;
  *(short8*)&lds[0][0][lo2] = pa1;
  *(short8*)&lds[0][1][lo]  = pb0;
  *(short8*)&lds[0][1][lo2] = pb1;

  f32x4 acc[4][4];
  f32x4 z = {0.f,0.f,0.f,0.f};
#pragma unroll
  for (int i = 0; i < 4; ++i)
#pragma unroll
    for (int j = 0; j < 4; ++j) acc[i][j] = z;

  for (int kt = 0; kt < NK; ++kt){
    __syncthreads();
    if (kt + 1 < NK){
      pa0 = *(const short8*)(Ab + (kt+1)*32);
      pa1 = *(const short8*)(Ab + (kt+1)*32 + 64*K);
      pb0 = *(const short8*)(Wb + (kt+1)*32);
      pb1 = *(const short8*)(Wb + (kt+1)*32 + 64*K);
    }
    const short* As = lds[kt & 1][0];
    const short* Bs = lds[kt & 1][1];
    short8 bfr[4];
#pragma unroll
    for (int nf = 0; nf < 4; ++nf)
      bfr[nf] = *(const short8*)&Bs[(wn*64 + nf*16 + (l & 15))*40 + (l >> 4)*8];
#pragma unroll
    for (int mf = 0; mf < 4; ++mf){
      short8 af = *(const short8*)&As[(wm*64 + mf*16 + (l & 15))*40 + (l >> 4)*8];
#pragma unroll
      for (int nf = 0; nf < 4; ++nf)
        acc[mf][nf] = __builtin_amdgcn_mfma_f32_16x16x32_bf16(af, bfr[nf], acc[mf][nf], 0, 0, 0);
    }
    if (kt + 1 < NK){
      int nb = (kt + 1) & 1;
      *(short8*)&lds[nb][0][lo]  = pa0;
      *(short8*)&lds[nb][0][lo2] = pa1;
      *(short8*)&lds[nb][1][lo]  = pb0;
      *(short8*)&lds[nb][1][lo2] = pb1;
    }
  }

  const int mrow0 = mt*128 + wm*64;
  const int ncol0 = nt*128 + wn*64;
#pragma unroll
  for (int nf = 0; nf < 4; ++nf){
    int n = ncol0 + nf*16 + (l & 15);      // n = g*1024 + jf*16 + jl
    int g  = n >> 10;
    int jfn = (n >> 4) & 63;
    int jl  = n & 15;
    float bs = bih[n] + bhh[n];
#pragma unroll
    for (int mf = 0; mf < 4; ++mf){
#pragma unroll
      for (int r = 0; r < 4; ++r){
        int m = mrow0 + mf*16 + (l >> 4)*4 + r;   // C/D: row=(l>>4)*4+r, col=l&15
        int b = m >> 9, t = m & 511;
        long idx = ((((long)t*8 + (b >> 4))*64 + jfn)*4 + g)*256 + (b & 15)*16 + jl;
        C[idx] = f2bf(acc[mf][nf][r] + bs);
      }
    }
  }
}

// ---------------- persistent LSTM scan (one launch per layer) ----------------
// grid (jf=64, bt=8) = 512 blocks x 256 thr; 2 blocks/CU co-resident.
// W_hh slice (64 rows x 1024 K = 128KB/block) register-resident, asm-pinned.
// Per step: prefetch xg, read h frags via agent-scope atomic u64 (sc0 sc1 -> MALL,
// L2 never invalidated, W stays hot), 32 MFMA/wave (4-way K-split), LDS reduce,
// elementwise, pack h via LDS -> wave-0 u64 atomic stores -> vmcnt(0) -> flag,
// poll flags of own bt-group. NO agent fences anywhere.
template<int LAYER>
__global__ __launch_bounds__(256, 2) void lstm_scan(
    short* __restrict__ hb0, short* __restrict__ hb1,
    const short* __restrict__ Wsw, const short* __restrict__ xg,
    const float* __restrict__ om, const float* __restrict__ hm, const float* __restrict__ cm,
    short* __restrict__ out0, float* __restrict__ dout,
    int* __restrict__ flags)     // [8 bt][512 t][64 jf] ints, pre-zeroed
{
  const int tid = threadIdx.x;
  const int l = tid & 63, wv = tid >> 6;
  const int jf = blockIdx.x, bt = blockIdx.y;

  // ---- load W fragments once; pin in registers (asm output can't be remat'd) ----
  short8 w[4][8];
#pragma unroll
  for (int g = 0; g < 4; ++g){
    const short8* wp = (const short8*)Wsw + ((g*64 + jf)*32 + wv*8)*64 + l;
#pragma unroll
    for (int ks = 0; ks < 8; ++ks) w[g][ks] = wp[ks*64];
  }
  {
    f32x4* wf = (f32x4*)w;
#pragma unroll
    for (int i = 0; i < 32; ++i) asm volatile("" : "+v"(wf[i]));
  }

  // ---- elementwise-role constants ----
  const int bl = tid >> 4, jl = tid & 15;
  const int jcol = jf*16 + jl;
  const long bj = (long)(bt*16 + bl)*H_ + jcol;
  const float mo = om[bj], mh = hm[bj], mc = cm[bj];
  float c = 0.f;
  const int lsrc = ((bl >> 2) << 4) | jl;   // lane holding acc row bl, col jl
  const int rr = bl & 3;
  const long hchunk = (long)(bt*32 + wv*8)*64 + l;   // consumer chunk base (16B units)

  // ---- producer (pack-lane, tid<64) constants ----
  const int pq = tid & 3, pbl = tid >> 2;
  const int jcol0 = jf*16 + pq*4;
  const long pchunk = ((long)(bt*32 + (jcol0 >> 5))*64 + (((jcol0 >> 3) & 3))*16 + pbl);
  const long pqw = pchunk*2 + ((pq & 1));   // u64 index of this lane's 8B

  __shared__ float red[16][256];
  __shared__ short sstage[256];
  int* fl = flags + (long)bt*T_*64;

  for (int t = 0; t < T_; ++t){
    // ---- prefetch xg for this step (latency hides under MFMA+reduce) ----
    const short* xgp = xg + (((long)t*8 + bt)*64 + jf)*1024;
    short xv0 = xgp[tid], xv1 = xgp[256 + tid], xv2 = xgp[512 + tid], xv3 = xgp[768 + tid];

    // ---- gather h via agent-scope u64 atomic loads (bypass L1/L2 -> MALL) ----
    const u64* hp = (const u64*)(t & 1 ? hb1 : hb0) + hchunk*2;
    short8 a[8];
#pragma unroll
    for (int ks = 0; ks < 8; ++ks){
      union { u64 q[2]; short8 v; } uu;
      uu.q[0] = __hip_atomic_load(hp + (long)ks*128,     __ATOMIC_RELAXED, __HIP_MEMORY_SCOPE_AGENT);
      uu.q[1] = __hip_atomic_load(hp + (long)ks*128 + 1, __ATOMIC_RELAXED, __HIP_MEMORY_SCOPE_AGENT);
      a[ks] = uu.v;
    }

    f32x4 acc[4];
    f32x4 z = {0.f,0.f,0.f,0.f};
#pragma unroll
    for (int g = 0; g < 4; ++g) acc[g] = z;
#pragma unroll
    for (int g = 0; g < 4; ++g)
#pragma unroll
      for (int ks = 0; ks < 8; ++ks)
        acc[g] = __builtin_amdgcn_mfma_f32_16x16x32_bf16(a[ks], w[g][ks], acc[g], 0, 0, 0);

#pragma unroll
    for (int g = 0; g < 4; ++g)
#pragma unroll
      for (int r = 0; r < 4; ++r)
        red[g*4 + r][tid] = acc[g][r];
    __syncthreads();

    // ---- elementwise (thread owns (bl, jl)) ----
    float gate[4];
    short xvv[4] = {xv0, xv1, xv2, xv3};
#pragma unroll
    for (int g = 0; g < 4; ++g){
      float s = red[g*4+rr][lsrc] + red[g*4+rr][64+lsrc]
              + red[g*4+rr][128+lsrc] + red[g*4+rr][192+lsrc];
      gate[g] = s + bf2f(xvv[g]);
    }
    float ii = sigm(gate[0]);
    float ff = sigm(gate[1]);
    float gg = tanh_(gate[2]);
    float oo = sigm(gate[3]);
    float c2 = ff*c + ii*gg;
    float h2 = oo*tanh_(c2);
    c = c2*mc;
    float hn = h2*mh;

    sstage[tid] = f2bf(hn);

    if (LAYER == 0){
      out0[((long)(bt*16 + bl)*T_ + t)*H_ + jcol] = f2bf(h2*mo);
    } else {
      dout[((long)(bt*16 + bl)*T_ + t)*H_ + jcol] = h2*mo;
      if (t == T_ - 1){
        dout[(long)B_*T_*H_ + bj] = hn;                    // hf
        dout[(long)B_*T_*H_ + (long)B_*H_ + bj] = c;       // cf
      }
    }

    if (t == T_ - 1) break;

    __syncthreads();   // sstage visible to pack lanes

    // ---- wave-0 packs + stores h (8B agent-scope), then sets flag ----
    if (tid < 64){
      u64 pk = *(const u64*)&sstage[pbl*16 + pq*4];
      u64* hx = (u64*)(t & 1 ? hb0 : hb1);
      __hip_atomic_store(hx + pqw, pk, __ATOMIC_RELAXED, __HIP_MEMORY_SCOPE_AGENT);
      asm volatile("s_waitcnt vmcnt(0)" ::: "memory");   // h globally visible (sc1 ack)
      if (tid == 0)
        __hip_atomic_store(&fl[t*64 + jf], 1, __ATOMIC_RELAXED, __HIP_MEMORY_SCOPE_AGENT);
      int guard = 0;
      while (__hip_atomic_load(&fl[t*64 + tid], __ATOMIC_RELAXED, __HIP_MEMORY_SCOPE_AGENT) == 0){
        __builtin_amdgcn_s_sleep(1);
        if (++guard > (1 << 18)) break;   // safety: wrong-answer instead of hang
      }
    }
    __syncthreads();
    __builtin_amdgcn_fence(__ATOMIC_ACQUIRE, "workgroup");  // compile-time ordering only
  }
}

extern "C" void kernel_launch(void* const* d_in, const int* in_sizes, int n_in,
                              void* d_out, int out_size, void* d_ws, size_t ws_size,
                              hipStream_t stream){
  const float* x    = (const float*)d_in[0];
  const float* Wih0 = (const float*)d_in[1];
  const float* Whh0 = (const float*)d_in[2];
  const float* bih0 = (const float*)d_in[3];
  const float* bhh0 = (const float*)d_in[4];
  const float* Wih1 = (const float*)d_in[5];
  const float* Whh1 = (const float*)d_in[6];
  const float* bih1 = (const float*)d_in[7];
  const float* bhh1 = (const float*)d_in[8];
  const float* omsk = (const float*)d_in[9];
  const float* hmsk = (const float*)d_in[10];
  const float* cmsk = (const float*)d_in[11];
  float* out = (float*)d_out;

  char* p = (char*)d_ws;
  auto alloc = [&](size_t bytes)->char*{
    char* r = p; p += (bytes + 255) & ~(size_t)255; return r;
  };
  short* xg      = (short*)alloc((size_t)65536*4096*2);   // swizzled xg (shared by both layers)
  short* x_bf    = (short*)alloc((size_t)33554432*2);     // x as bf16, [b*T+t][512]
  short* out0_bf = (short*)alloc((size_t)67108864*2);     // layer-0 outputs, [b*T+t][1024] bf16
  short* wih0_bf = (short*)alloc((size_t)2097152*2);
  short* wih1_bf = (short*)alloc((size_t)4194304*2);
  short* whh0_sw = (short*)alloc((size_t)4194304*2);
  short* whh1_sw = (short*)alloc((size_t)4194304*2);
  short* hb0     = (short*)alloc((size_t)131072*2);
  short* hb1     = (short*)alloc((size_t)131072*2);
  int*   flags0  = (int*)alloc((size_t)8*512*64*4);       // 1 MB
  int*   flags1  = (int*)alloc((size_t)8*512*64*4);       // 1 MB
  if ((size_t)(p - (char*)d_ws) > ws_size) return;   // workspace too small — bail

  // barrier flags must be zero at scan start (deterministic across graph replays)
  hipMemsetAsync(flags0, 0, (size_t)8*512*64*4, stream);
  hipMemsetAsync(flags1, 0, (size_t)8*512*64*4, stream);

  // converts / weight swizzles
  cvt_bf16<<<33554432/4/256, 256, 0, stream>>>(x,    x_bf,    33554432/4);
  cvt_bf16<<<2097152/4/256,  256, 0, stream>>>(Wih0, wih0_bf, 2097152/4);
  cvt_bf16<<<4194304/4/256,  256, 0, stream>>>(Wih1, wih1_bf, 4194304/4);
  swz_whh <<<524288/256,     256, 0, stream>>>(Whh0, whh0_sw);
  swz_whh <<<524288/256,     256, 0, stream>>>(Whh1, whh1_sw);

  // ---- layer 0 ----
  proj_gemm<512><<<dim3(32, 512), 256, 0, stream>>>(x_bf, wih0_bf, bih0, bhh0, xg);
  hipMemsetAsync(hb0, 0, 262144, stream);
  lstm_scan<0><<<dim3(64, 8), 256, 0, stream>>>(hb0, hb1, whh0_sw, xg,
      omsk, hmsk, cmsk, out0_bf, nullptr, flags0);

  // ---- layer 1 ----
  proj_gemm<1024><<<dim3(32, 512), 256, 0, stream>>>(out0_bf, wih1_bf, bih1, bhh1, xg);
  hipMemsetAsync(hb0, 0, 262144, stream);
  lstm_scan<1><<<dim3(64, 8), 256, 0, stream>>>(hb0, hb1, whh1_sw, xg,
      omsk + 131072, hmsk + 131072, cmsk + 131072, nullptr, out, flags1);
}

// Round 4
// 8856.799 us; speedup vs baseline: 6.4923x; 1.0868x over previous
//
#include <hip/hip_runtime.h>

// Problem constants
#define B_  128
#define T_  512
#define I_  512
#define H_  1024
#define G4  4096   // 4*H

typedef __attribute__((ext_vector_type(8))) short   short8;
typedef __attribute__((ext_vector_type(4))) short   short4v;
typedef __attribute__((ext_vector_type(4))) float   f32x4;
typedef unsigned long long u64;

__device__ __forceinline__ float bf2f(short u){
  return __uint_as_float(((unsigned)(unsigned short)u) << 16);
}
__device__ __forceinline__ short f2bf(float f){
  unsigned u = __float_as_uint(f);
  unsigned r = (u + 0x7FFFu + ((u >> 16) & 1u)) >> 16;  // RNE
  return (short)r;
}
__device__ __forceinline__ float sigm(float x){ return 1.0f/(1.0f + __expf(-x)); }
__device__ __forceinline__ float tanh_(float x){ return 1.0f - 2.0f/(__expf(2.0f*x) + 1.0f); }

// ---------------- fp32 -> bf16 elementwise convert (vectorized x4) ----------------
__global__ __launch_bounds__(256) void cvt_bf16(const float* __restrict__ in,
                                                short* __restrict__ out, int nq){
  int i = blockIdx.x*256 + threadIdx.x;
  if (i >= nq) return;
  float4 v = ((const float4*)in)[i];
  short4v o; o.x = f2bf(v.x); o.y = f2bf(v.y); o.z = f2bf(v.z); o.w = f2bf(v.w);
  ((short4v*)out)[i] = o;
}

// ---------------- W_hh fp32 [4096][1024] -> bf16 MFMA-fragment-swizzled ----------------
// out chunk index c = ((g*64 + jf)*32 + s)*64 + l ; chunk = 8 bf16 (16B)
// represents W[g*1024 + jf*16 + (l&15)][s*32 + (l>>4)*8 + e]
__global__ __launch_bounds__(256) void swz_whh(const float* __restrict__ W,
                                               short* __restrict__ out){
  int c = blockIdx.x*256 + threadIdx.x;      // 0 .. 524287
  int l = c & 63, s = (c >> 6) & 31, jf = (c >> 11) & 63, g = c >> 17;
  long row = (long)(g*1024 + jf*16 + (l & 15));
  int col = s*32 + (l >> 4)*8;
  const float* src = W + row*H_ + col;
  short8 o;
#pragma unroll
  for (int e = 0; e < 8; ++e) o[e] = f2bf(src[e]);
  ((short8*)out)[c] = o;
}

// ---------------- projection GEMM: C[m,n] = sum_k A[m,k]*W[n,k] + bih[n]+bhh[n] ----------------
// Output written in scan-swizzled xg layout:
//   idx = ((((t*8 + bt)*64 + jf)*4 + g)*256 + bl*16 + jl
template<int K>
__global__ __launch_bounds__(256) void proj_gemm(const short* __restrict__ A,
                                                 const short* __restrict__ W,
                                                 const float* __restrict__ bih,
                                                 const float* __restrict__ bhh,
                                                 short* __restrict__ C){
  __shared__ short lds[2][2][128*40];  // [buf][A/B][row*40+col], pad 40 kills conflicts
  const int tid = threadIdx.x;
  const int l  = tid & 63, wv = tid >> 6;
  const int wm = wv >> 1,  wn = wv & 1;
  const int nt = blockIdx.x, mt = blockIdx.y;
  const int r0 = tid >> 2, cb = (tid & 3) * 8;
  const short* Ab = A + (long)(mt*128 + r0)*K + cb;
  const short* Wb = W + (long)(nt*128 + r0)*K + cb;
  const int lo  = r0*40 + cb;
  const int lo2 = lo + 64*40;
  const int NK = K/32;

  short8 pa0 = *(const short8*)(Ab);
  short8 pa1 = *(const short8*)(Ab + 64*K);
  short8 pb0 = *(const short8*)(Wb);
  short8 pb1 = *(const short8*)(Wb + 64*K);
  *(short8*)&lds[0][0][lo]  = pa0;
  *(short8*)&lds[0][0][lo2] = pa1;
  *(short8*)&lds[0][1][lo]  = pb0;
  *(short8*)&lds[0][1][lo2] = pb1;

  f32x4 acc[4][4];
  f32x4 z = {0.f,0.f,0.f,0.f};
#pragma unroll
  for (int i = 0; i < 4; ++i)
#pragma unroll
    for (int j = 0; j < 4; ++j) acc[i][j] = z;

  for (int kt = 0; kt < NK; ++kt){
    __syncthreads();
    if (kt + 1 < NK){
      pa0 = *(const short8*)(Ab + (kt+1)*32);
      pa1 = *(const short8*)(Ab + (kt+1)*32 + 64*K);
      pb0 = *(const short8*)(Wb + (kt+1)*32);
      pb1 = *(const short8*)(Wb + (kt+1)*32 + 64*K);
    }
    const short* As = lds[kt & 1][0];
    const short* Bs = lds[kt & 1][1];
    short8 bfr[4];
#pragma unroll
    for (int nf = 0; nf < 4; ++nf)
      bfr[nf] = *(const short8*)&Bs[(wn*64 + nf*16 + (l & 15))*40 + (l >> 4)*8];
#pragma unroll
    for (int mf = 0; mf < 4; ++mf){
      short8 af = *(const short8*)&As[(wm*64 + mf*16 + (l & 15))*40 + (l >> 4)*8];
#pragma unroll
      for (int nf = 0; nf < 4; ++nf)
        acc[mf][nf] = __builtin_amdgcn_mfma_f32_16x16x32_bf16(af, bfr[nf], acc[mf][nf], 0, 0, 0);
    }
    if (kt + 1 < NK){
      int nb = (kt + 1) & 1;
      *(short8*)&lds[nb][0][lo]  = pa0;
      *(short8*)&lds[nb][0][lo2] = pa1;
      *(short8*)&lds[nb][1][lo]  = pb0;
      *(short8*)&lds[nb][1][lo2] = pb1;
    }
  }

  const int mrow0 = mt*128 + wm*64;
  const int ncol0 = nt*128 + wn*64;
#pragma unroll
  for (int nf = 0; nf < 4; ++nf){
    int n = ncol0 + nf*16 + (l & 15);      // n = g*1024 + jf*16 + jl
    int g  = n >> 10;
    int jfn = (n >> 4) & 63;
    int jl  = n & 15;
    float bs = bih[n] + bhh[n];
#pragma unroll
    for (int mf = 0; mf < 4; ++mf){
#pragma unroll
      for (int r = 0; r < 4; ++r){
        int m = mrow0 + mf*16 + (l >> 4)*4 + r;   // C/D: row=(l>>4)*4+r, col=l&15
        int b = m >> 9, t = m & 511;
        long idx = ((((long)t*8 + (b >> 4))*64 + jfn)*4 + g)*256 + (b & 15)*16 + jl;
        C[idx] = f2bf(acc[mf][nf][r] + bs);
      }
    }
  }
}

// ---------------- persistent LSTM scan (one launch per layer) ----------------
// grid (jf=64, bt=8) = 512 blocks x 256 thr; 2 blocks/CU co-resident.
// W_hh slice register(AGPR)-resident, asm-pinned. Per step:
//   load h slice (agent-scope u64, MALL-coherent) -> 32 MFMA/wave (4-way K-split)
//   -> LDS reduce -> elementwise -> wave-local h pack (ds_write_b16 + lgkmcnt,
//   no extra barrier) -> u64 agent store -> vmcnt(0) -> barrier -> flag ->
//   [xg prefetch + out stores overlap poll] -> per-wave poll of its 16 slice flags.
template<int LAYER>
__global__ __launch_bounds__(256, 2) void lstm_scan(
    short* __restrict__ hb0, short* __restrict__ hb1,
    const short* __restrict__ Wsw, const short* __restrict__ xg,
    const float* __restrict__ om, const float* __restrict__ hm, const float* __restrict__ cm,
    short* __restrict__ out0, float* __restrict__ dout,
    int* __restrict__ flags)     // [8 bt][512 t][64 jf] ints, pre-zeroed
{
  const int tid = threadIdx.x;
  const int l = tid & 63, wv = tid >> 6;
  const int jf = blockIdx.x, bt = blockIdx.y;

  // ---- load W fragments once; pin (lives in unified VGPR/AGPR file) ----
  short8 w[4][8];
#pragma unroll
  for (int g = 0; g < 4; ++g){
    const short8* wp = (const short8*)Wsw + ((g*64 + jf)*32 + wv*8)*64 + l;
#pragma unroll
    for (int ks = 0; ks < 8; ++ks) w[g][ks] = wp[ks*64];
  }
  {
    f32x4* wf = (f32x4*)w;
#pragma unroll
    for (int i = 0; i < 32; ++i) asm volatile("" : "+v"(wf[i]));
  }

  // ---- elementwise-role constants ----
  const int bl = tid >> 4, jl = tid & 15;
  const int jcol = jf*16 + jl;
  const long bj = (long)(bt*16 + bl)*H_ + jcol;
  const float mo = om[bj], mh = hm[bj], mc = cm[bj];
  float c = 0.f;
  const int lsrc = ((bl >> 2) << 4) | jl;   // lane holding acc row bl, col jl
  const int rr = bl & 3;
  const long hchunk = (long)(bt*32 + wv*8)*64 + l;   // consumer chunk base (16B units)

  // ---- producer constants: block's h output = one contiguous 512B region ----
  // chunk-in-region offC = (jl>>3)*16 + bl ; region chunk base C0
  const int offC = (jl >> 3)*16 + bl;
  const int sidx = offC*8 + (jl & 7);                 // sstage short index
  const long C0  = (long)(bt*32 + (jf >> 1))*64 + (jf & 1)*32;
  // pack lanes p<16 of wave wv store u64 index qidx of the region
  const int qidx = (l < 8) ? (8*wv + l) : (l < 16 ? (32 + 8*wv + (l - 8)) : 0);

  __shared__ float red[16][256];
  __shared__ __align__(16) short sstage[256];
  int* fl = flags + (long)bt*T_*64;

  // xg prefetch for t=0
  {
    const short* x0 = xg + (((long)bt)*64 + jf)*1024;
    // nothing else; loads below
  }
  const short* xg0 = xg + (((long)bt)*64 + jf)*1024;
  short xv0 = xg0[tid], xv1 = xg0[256 + tid], xv2 = xg0[512 + tid], xv3 = xg0[768 + tid];

  for (int t = 0; t < T_; ++t){
    // ---- gather h slice via agent-scope u64 atomic loads (MALL-coherent) ----
    const u64* hp = (const u64*)(t & 1 ? hb1 : hb0) + hchunk*2;
    short8 a[8];
#pragma unroll
    for (int ks = 0; ks < 8; ++ks){
      union { u64 q[2]; short8 v; } uu;
      uu.q[0] = __hip_atomic_load(hp + (long)ks*128,     __ATOMIC_RELAXED, __HIP_MEMORY_SCOPE_AGENT);
      uu.q[1] = __hip_atomic_load(hp + (long)ks*128 + 1, __ATOMIC_RELAXED, __HIP_MEMORY_SCOPE_AGENT);
      a[ks] = uu.v;
    }

    f32x4 acc[4];
    f32x4 z = {0.f,0.f,0.f,0.f};
#pragma unroll
    for (int g = 0; g < 4; ++g) acc[g] = z;
#pragma unroll
    for (int g = 0; g < 4; ++g)
#pragma unroll
      for (int ks = 0; ks < 8; ++ks)
        acc[g] = __builtin_amdgcn_mfma_f32_16x16x32_bf16(a[ks], w[g][ks], acc[g], 0, 0, 0);

#pragma unroll
    for (int g = 0; g < 4; ++g)
#pragma unroll
      for (int r = 0; r < 4; ++r)
        red[g*4 + r][tid] = acc[g][r];
    __syncthreads();

    // ---- elementwise (thread owns (bl, jl)); xv* prefetched last iteration ----
    float gate[4];
    short xvv[4] = {xv0, xv1, xv2, xv3};
#pragma unroll
    for (int g = 0; g < 4; ++g){
      float s = red[g*4+rr][lsrc] + red[g*4+rr][64+lsrc]
              + red[g*4+rr][128+lsrc] + red[g*4+rr][192+lsrc];
      gate[g] = s + bf2f(xvv[g]);
    }
    float ii = sigm(gate[0]);
    float ff = sigm(gate[1]);
    float gg = tanh_(gate[2]);
    float oo = sigm(gate[3]);
    float c2 = ff*c + ii*gg;
    float h2 = oo*tanh_(c2);
    c = c2*mc;
    float hn = h2*mh;

    if (t < T_ - 1){
      // ---- wave-local pack: LDS write, wave-ordered, lanes<16 store u64 ----
      sstage[sidx] = f2bf(hn);
      asm volatile("s_waitcnt lgkmcnt(0)" ::: "memory");   // this wave's ds_write done
      if (l < 16){
        u64 pk = *(const u64*)&sstage[qidx*4];
        u64* hx = (u64*)(t & 1 ? hb0 : hb1);
        __hip_atomic_store(hx + C0*2 + qidx, pk, __ATOMIC_RELAXED, __HIP_MEMORY_SCOPE_AGENT);
      }
      asm volatile("s_waitcnt vmcnt(0)" ::: "memory");     // h at MALL (device-visible)
      __syncthreads();                                     // all 4 waves' h stores ack'd
      if (tid == 0)
        __hip_atomic_store(&fl[t*64 + jf], 1, __ATOMIC_RELAXED, __HIP_MEMORY_SCOPE_AGENT);
    }

    // ---- xg prefetch for t+1 (overlaps poll) ----
    short nx0 = xv0, nx1 = xv1, nx2 = xv2, nx3 = xv3;
    if (t + 1 < T_){
      const short* xgn = xg + (((long)(t+1)*8 + bt)*64 + jf)*1024;
      nx0 = xgn[tid]; nx1 = xgn[256 + tid]; nx2 = xgn[512 + tid]; nx3 = xgn[768 + tid];
    }

    // ---- out stores (overlap poll; off the flag's critical path) ----
    if (LAYER == 0){
      out0[((long)(bt*16 + bl)*T_ + t)*H_ + jcol] = f2bf(h2*mo);
    } else {
      dout[((long)(bt*16 + bl)*T_ + t)*H_ + jcol] = h2*mo;
      if (t == T_ - 1){
        dout[(long)B_*T_*H_ + bj] = hn;                    // hf
        dout[(long)B_*T_*H_ + (long)B_*H_ + bj] = c;       // cf
      }
    }

    if (t == T_ - 1) break;

    // ---- per-wave poll: wave wv needs K-cols [wv*256, wv*256+256) = jf [wv*16, +16) ----
    if (l < 16){
      int guard = 0;
      while (__hip_atomic_load(&fl[t*64 + wv*16 + l], __ATOMIC_RELAXED, __HIP_MEMORY_SCOPE_AGENT) == 0){
        if (++guard > (1 << 20)) break;   // safety: wrong-answer instead of hang
      }
    }
    __builtin_amdgcn_fence(__ATOMIC_ACQUIRE, "workgroup");  // order h loads after poll (cheap)

    xv0 = nx0; xv1 = nx1; xv2 = nx2; xv3 = nx3;
  }
}

extern "C" void kernel_launch(void* const* d_in, const int* in_sizes, int n_in,
                              void* d_out, int out_size, void* d_ws, size_t ws_size,
                              hipStream_t stream){
  const float* x    = (const float*)d_in[0];
  const float* Wih0 = (const float*)d_in[1];
  const float* Whh0 = (const float*)d_in[2];
  const float* bih0 = (const float*)d_in[3];
  const float* bhh0 = (const float*)d_in[4];
  const float* Wih1 = (const float*)d_in[5];
  const float* Whh1 = (const float*)d_in[6];
  const float* bih1 = (const float*)d_in[7];
  const float* bhh1 = (const float*)d_in[8];
  const float* omsk = (const float*)d_in[9];
  const float* hmsk = (const float*)d_in[10];
  const float* cmsk = (const float*)d_in[11];
  float* out = (float*)d_out;

  char* p = (char*)d_ws;
  auto alloc = [&](size_t bytes)->char*{
    char* r = p; p += (bytes + 255) & ~(size_t)255; return r;
  };
  short* xg      = (short*)alloc((size_t)65536*4096*2);   // swizzled xg (shared by both layers)
  short* x_bf    = (short*)alloc((size_t)33554432*2);     // x as bf16, [b*T+t][512]
  short* out0_bf = (short*)alloc((size_t)67108864*2);     // layer-0 outputs, [b*T+t][1024] bf16
  short* wih0_bf = (short*)alloc((size_t)2097152*2);
  short* wih1_bf = (short*)alloc((size_t)4194304*2);
  short* whh0_sw = (short*)alloc((size_t)4194304*2);
  short* whh1_sw = (short*)alloc((size_t)4194304*2);
  short* hb0     = (short*)alloc((size_t)131072*2);
  short* hb1     = (short*)alloc((size_t)131072*2);
  int*   flags0  = (int*)alloc((size_t)8*512*64*4);       // 1 MB
  int*   flags1  = (int*)alloc((size_t)8*512*64*4);       // 1 MB
  if ((size_t)(p - (char*)d_ws) > ws_size) return;   // workspace too small — bail

  // barrier flags must be zero at scan start (deterministic across graph replays)
  hipMemsetAsync(flags0, 0, (size_t)8*512*64*4, stream);
  hipMemsetAsync(flags1, 0, (size_t)8*512*64*4, stream);

  // converts / weight swizzles
  cvt_bf16<<<33554432/4/256, 256, 0, stream>>>(x,    x_bf,    33554432/4);
  cvt_bf16<<<2097152/4/256,  256, 0, stream>>>(Wih0, wih0_bf, 2097152/4);
  cvt_bf16<<<4194304/4/256,  256, 0, stream>>>(Wih1, wih1_bf, 4194304/4);
  swz_whh <<<524288/256,     256, 0, stream>>>(Whh0, whh0_sw);
  swz_whh <<<524288/256,     256, 0, stream>>>(Whh1, whh1_sw);

  // ---- layer 0 ----
  proj_gemm<512><<<dim3(32, 512), 256, 0, stream>>>(x_bf, wih0_bf, bih0, bhh0, xg);
  hipMemsetAsync(hb0, 0, 262144, stream);
  lstm_scan<0><<<dim3(64, 8), 256, 0, stream>>>(hb0, hb1, whh0_sw, xg,
      omsk, hmsk, cmsk, out0_bf, nullptr, flags0);

  // ---- layer 1 ----
  proj_gemm<1024><<<dim3(32, 512), 256, 0, stream>>>(out0_bf, wih1_bf, bih1, bhh1, xg);
  hipMemsetAsync(hb0, 0, 262144, stream);
  lstm_scan<1><<<dim3(64, 8), 256, 0, stream>>>(hb0, hb1, whh1_sw, xg,
      omsk + 131072, hmsk + 131072, cmsk + 131072, nullptr, out, flags1);
}